// Round 2
// baseline (729.158 us; speedup 1.0000x reference)
//
#include <hip/hip_runtime.h>
#include <hip/hip_bf16.h>

using bf16   = __bf16;
using bf16x8 = __attribute__((ext_vector_type(8))) __bf16;
using bf16x4 = __attribute__((ext_vector_type(4))) __bf16;
using f32x4  = __attribute__((ext_vector_type(4))) float;

#define MFMA16(W, X, C) __builtin_amdgcn_mfma_f32_16x16x32_bf16((W), (X), (C), 0, 0, 0)

__device__ __forceinline__ float hsw(float x) {
    return x * fminf(fmaxf(x + 3.f, 0.f), 6.f) * (1.f / 6.f);
}
__device__ __forceinline__ float lrelu(float x) {
    return x >= 0.f ? x : 0.1f * x;
}
__device__ __forceinline__ bf16x8 zero8() {
    bf16x8 t;
#pragma unroll
    for (int b = 0; b < 8; ++b) t[b] = (bf16)0.f;
    return t;
}
__device__ __forceinline__ f32x4 zero4f() {
    f32x4 t = {0.f, 0.f, 0.f, 0.f};
    return t;
}

// Prearrange fp32 weight W[KTOT x COUT] (row-major, HWIO with k = tap*Cin+ci)
// into LDS as MFMA A-operand fragments.
// frag f = ks*NCT+ct: lane holds j = ct*16 + (lane&15) (out channel = MFMA D-row),
// elements b=0..7 at k = ks*32 + (lane>>4)*8 + b.   [m89/m91-verified mapping]
template <int KTOT, int COUT>
__device__ void fill_w(bf16* dst, const float* __restrict__ W, int tid) {
    constexpr int NKS = KTOT / 32, NCT = COUT / 16;
    for (int idx = tid; idx < NKS * NCT * 64; idx += 256) {
        int lane = idx & 63;
        int f = idx >> 6;
        int ct = f % NCT, ks = f / NCT;
        int j = ct * 16 + (lane & 15);
        int kb = ks * 32 + ((lane >> 4) << 3);
        bf16* d = dst + (size_t)idx * 8;
#pragma unroll
        for (int b = 0; b < 8; ++b) d[b] = (bf16)W[(size_t)(kb + b) * COUT + j];
    }
}

// BN folding: scale = g*rsqrt(v+eps), shift = b - m*scale; channels [off,off+n)
__device__ void fill_bn_(float* sc, float* sh, const float* __restrict__ p,
                         int C, int off, int n, int tid) {
    for (int c = tid; c < n; c += 256) {
        float g = p[off + c], b = p[C + off + c];
        float m = p[2 * C + off + c], v = p[3 * C + off + c];
        float s = g * rsqrtf(v + 1e-3f);
        sc[c] = s;
        sh[c] = b - m * s;
    }
}

// ---------------- k_head: y = hswish(bn1(x@cv1)); x2 = leaky(bncat_hi(x@cv2p))
__global__ __launch_bounds__(256) void k_head(
    const float* __restrict__ x, const float* __restrict__ w1,
    const float* __restrict__ bn1, const float* __restrict__ w2p,
    const float* __restrict__ bncat, bf16* __restrict__ y, bf16* __restrict__ x2) {
    __shared__ bf16 wa[128 * 64], wb[128 * 64];
    __shared__ float sca[64], sha[64], scb[64], shb[64];
    int tid = threadIdx.x;
    fill_w<128, 64>(wa, w1, tid);
    fill_w<128, 64>(wb, w2p, tid);
    fill_bn_(sca, sha, bn1, 64, 0, 64, tid);
    fill_bn_(scb, shb, bncat, 128, 64, 64, tid);
    __syncthreads();
    int lane = tid & 63, wid = tid >> 6;
    int lr = lane & 15, lg = lane >> 4;
    int m0 = blockIdx.x * 128 + wid * 32;

    f32x4 accy[2][4], accx[2][4];
#pragma unroll
    for (int rt = 0; rt < 2; ++rt)
#pragma unroll
        for (int ct = 0; ct < 4; ++ct) { accy[rt][ct] = zero4f(); accx[rt][ct] = zero4f(); }

#pragma unroll
    for (int ks = 0; ks < 4; ++ks) {
        bf16x8 xa[2];
#pragma unroll
        for (int rt = 0; rt < 2; ++rt) {
            const float* p = x + (size_t)(m0 + rt * 16 + lr) * 128 + ks * 32 + lg * 8;
            f32x4 v0 = *(const f32x4*)p;
            f32x4 v1 = *(const f32x4*)(p + 4);
            bf16x8 t;
#pragma unroll
            for (int b = 0; b < 4; ++b) { t[b] = (bf16)v0[b]; t[b + 4] = (bf16)v1[b]; }
            xa[rt] = t;
        }
#pragma unroll
        for (int ct = 0; ct < 4; ++ct) {
            bf16x8 fa = *(const bf16x8*)(wa + (size_t)((ks * 4 + ct) * 64 + lane) * 8);
            bf16x8 fb = *(const bf16x8*)(wb + (size_t)((ks * 4 + ct) * 64 + lane) * 8);
#pragma unroll
            for (int rt = 0; rt < 2; ++rt) {
                accy[rt][ct] = MFMA16(fa, xa[rt], accy[rt][ct]);
                accx[rt][ct] = MFMA16(fb, xa[rt], accx[rt][ct]);
            }
        }
    }
#pragma unroll
    for (int rt = 0; rt < 2; ++rt) {
        size_t r = (size_t)(m0 + rt * 16 + lr);
#pragma unroll
        for (int ct = 0; ct < 4; ++ct) {
            int j0 = ct * 16 + lg * 4;
            f32x4 s4 = *(const f32x4*)(sca + j0), h4 = *(const f32x4*)(sha + j0);
            f32x4 a = accy[rt][ct];
            bf16x4 oy, ox;
#pragma unroll
            for (int b = 0; b < 4; ++b) oy[b] = (bf16)hsw(a[b] * s4[b] + h4[b]);
            *(bf16x4*)(y + r * 64 + j0) = oy;
            s4 = *(const f32x4*)(scb + j0);
            h4 = *(const f32x4*)(shb + j0);
            a = accx[rt][ct];
#pragma unroll
            for (int b = 0; b < 4; ++b) ox[b] = (bf16)lrelu(a[b] * s4[b] + h4[b]);
            *(bf16x4*)(x2 + r * 64 + j0) = ox;
        }
    }
}

// ---------------- k_cb64: out = hswish(bn(in @ W)), 1x1 64->64
__global__ __launch_bounds__(256) void k_cb64(
    const bf16* __restrict__ in, const float* __restrict__ W,
    const float* __restrict__ bnp, bf16* __restrict__ out) {
    __shared__ bf16 wl[64 * 64];
    __shared__ float sc[64], sh[64];
    int tid = threadIdx.x;
    fill_w<64, 64>(wl, W, tid);
    fill_bn_(sc, sh, bnp, 64, 0, 64, tid);
    __syncthreads();
    int lane = tid & 63, wid = tid >> 6;
    int lr = lane & 15, lg = lane >> 4;
    bf16x8 wf[2][4];
#pragma unroll
    for (int ks = 0; ks < 2; ++ks)
#pragma unroll
        for (int ct = 0; ct < 4; ++ct)
            wf[ks][ct] = *(const bf16x8*)(wl + (size_t)((ks * 4 + ct) * 64 + lane) * 8);

    int m0 = blockIdx.x * 256 + wid * 64;
    f32x4 acc[4][4];
#pragma unroll
    for (int rt = 0; rt < 4; ++rt)
#pragma unroll
        for (int ct = 0; ct < 4; ++ct) acc[rt][ct] = zero4f();

#pragma unroll
    for (int ks = 0; ks < 2; ++ks) {
        bf16x8 xa[4];
#pragma unroll
        for (int rt = 0; rt < 4; ++rt)
            xa[rt] = *(const bf16x8*)(in + (size_t)(m0 + rt * 16 + lr) * 64 + ks * 32 + lg * 8);
#pragma unroll
        for (int ct = 0; ct < 4; ++ct)
#pragma unroll
            for (int rt = 0; rt < 4; ++rt)
                acc[rt][ct] = MFMA16(wf[ks][ct], xa[rt], acc[rt][ct]);
    }
#pragma unroll
    for (int rt = 0; rt < 4; ++rt) {
        size_t r = (size_t)(m0 + rt * 16 + lr);
#pragma unroll
        for (int ct = 0; ct < 4; ++ct) {
            int j0 = ct * 16 + lg * 4;
            f32x4 s4 = *(const f32x4*)(sc + j0), h4 = *(const f32x4*)(sh + j0);
            f32x4 a = acc[rt][ct];
            bf16x4 o;
#pragma unroll
            for (int b = 0; b < 4; ++b) o[b] = (bf16)hsw(a[b] * s4[b] + h4[b]);
            *(bf16x4*)(out + r * 64 + j0) = o;
        }
    }
}

// ---------------- k_c3: y += hswish(bn(conv3x3_same(in, W)))   (in-place residual)
__global__ __launch_bounds__(256) void k_c3(
    const bf16* __restrict__ in, const float* __restrict__ W,
    const float* __restrict__ bnp, bf16* __restrict__ y) {
    __shared__ bf16 wl[576 * 64];  // 73.7 KB
    __shared__ float sc[64], sh[64];
    int tid = threadIdx.x;
    fill_w<576, 64>(wl, W, tid);
    fill_bn_(sc, sh, bnp, 64, 0, 64, tid);
    __syncthreads();
    int lane = tid & 63, wid = tid >> 6;
    int lr = lane & 15, lg = lane >> 4;
    int m0 = blockIdx.x * 256 + wid * 64;

    int row[4], wc[4], hr[4];
#pragma unroll
    for (int rt = 0; rt < 4; ++rt) {
        int r = m0 + rt * 16 + lr;
        row[rt] = r;
        int q = r / 160;
        wc[rt] = r - q * 160;
        hr[rt] = q % 160;
    }
    f32x4 acc[4][4];
#pragma unroll
    for (int rt = 0; rt < 4; ++rt)
#pragma unroll
        for (int ct = 0; ct < 4; ++ct) acc[rt][ct] = zero4f();

#pragma unroll
    for (int tap = 0; tap < 9; ++tap) {
        const int dy = tap / 3 - 1, dx = tap % 3 - 1;
        const int roff = dy * 160 + dx;
#pragma unroll
        for (int ks2 = 0; ks2 < 2; ++ks2) {
            int ks = tap * 2 + ks2;
            bf16x8 xa[4];
#pragma unroll
            for (int rt = 0; rt < 4; ++rt) {
                bool v = ((unsigned)(hr[rt] + dy) < 160u) && ((unsigned)(wc[rt] + dx) < 160u);
                bf16x8 t = zero8();
                if (v)
                    t = *(const bf16x8*)(in + (size_t)(row[rt] + roff) * 64 + ks2 * 32 + lg * 8);
                xa[rt] = t;
            }
            bf16x8 wfr[4];
#pragma unroll
            for (int ct = 0; ct < 4; ++ct)
                wfr[ct] = *(const bf16x8*)(wl + (size_t)((ks * 4 + ct) * 64 + lane) * 8);
#pragma unroll
            for (int ct = 0; ct < 4; ++ct)
#pragma unroll
                for (int rt = 0; rt < 4; ++rt)
                    acc[rt][ct] = MFMA16(wfr[ct], xa[rt], acc[rt][ct]);
        }
    }
#pragma unroll
    for (int rt = 0; rt < 4; ++rt) {
        size_t r = (size_t)row[rt];
#pragma unroll
        for (int ct = 0; ct < 4; ++ct) {
            int j0 = ct * 16 + lg * 4;
            f32x4 s4 = *(const f32x4*)(sc + j0), h4 = *(const f32x4*)(sh + j0);
            f32x4 a = acc[rt][ct];
            bf16x4 old = *(const bf16x4*)(y + r * 64 + j0);
            bf16x4 o;
#pragma unroll
            for (int b = 0; b < 4; ++b)
                o[b] = (bf16)((float)old[b] + hsw(a[b] * s4[b] + h4[b]));
            *(bf16x4*)(y + r * 64 + j0) = o;
        }
    }
}

// ---------------- k_tail: out = hswish(bn4( [leaky(bncat_lo(y@cv3)) | x2] @ cv4 ))
__global__ __launch_bounds__(256) void k_tail(
    const bf16* __restrict__ y, const bf16* __restrict__ x2,
    const float* __restrict__ w3, const float* __restrict__ w4,
    const float* __restrict__ bncat, const float* __restrict__ bn4,
    float* __restrict__ out) {
    __shared__ bf16 w3l[64 * 64];
    __shared__ bf16 w4l[128 * 128];
    __shared__ float sc1[64], sh1[64], sc4[128], sh4[128];
    __shared__ bf16 tl[4 * 32 * 64];  // per-wave 32x64 bf16 tile, XOR-swizzled
    int tid = threadIdx.x;
    fill_w<64, 64>(w3l, w3, tid);
    fill_w<128, 128>(w4l, w4, tid);
    fill_bn_(sc1, sh1, bncat, 128, 0, 64, tid);
    fill_bn_(sc4, sh4, bn4, 128, 0, 128, tid);
    __syncthreads();
    int lane = tid & 63, wid = tid >> 6;
    int lr = lane & 15, lg = lane >> 4;
    int m0 = blockIdx.x * 128 + wid * 32;
    char* tlw = (char*)(tl + (size_t)wid * 32 * 64);

    // GEMM1: x1 = y @ cv3, fold bn_cat[:64] + leaky, stash bf16 tile in LDS
    f32x4 a1[2][4];
#pragma unroll
    for (int rt = 0; rt < 2; ++rt)
#pragma unroll
        for (int ct = 0; ct < 4; ++ct) a1[rt][ct] = zero4f();
#pragma unroll
    for (int ks = 0; ks < 2; ++ks) {
        bf16x8 xa[2];
#pragma unroll
        for (int rt = 0; rt < 2; ++rt)
            xa[rt] = *(const bf16x8*)(y + (size_t)(m0 + rt * 16 + lr) * 64 + ks * 32 + lg * 8);
#pragma unroll
        for (int ct = 0; ct < 4; ++ct) {
            bf16x8 wfr = *(const bf16x8*)(w3l + (size_t)((ks * 4 + ct) * 64 + lane) * 8);
#pragma unroll
            for (int rt = 0; rt < 2; ++rt) a1[rt][ct] = MFMA16(wfr, xa[rt], a1[rt][ct]);
        }
    }
#pragma unroll
    for (int rt = 0; rt < 2; ++rt) {
        int rr = rt * 16 + lr;
#pragma unroll
        for (int ct = 0; ct < 4; ++ct) {
            int j0 = ct * 16 + lg * 4;
            f32x4 s4 = *(const f32x4*)(sc1 + j0), h4 = *(const f32x4*)(sh1 + j0);
            f32x4 a = a1[rt][ct];
            bf16x4 o;
#pragma unroll
            for (int b = 0; b < 4; ++b) o[b] = (bf16)lrelu(a[b] * s4[b] + h4[b]);
            int byo = (rr * 128 + j0 * 2) ^ ((rr & 7) << 4);
            *(bf16x4*)(tlw + byo) = o;
        }
    }
    // Defensive: guarantee cross-lane LDS write->read visibility/ordering.
    __syncthreads();

    // GEMM2: K=128 (k 0..63 from LDS tile, k 64..127 from x2)
    f32x4 a2[2][8];
#pragma unroll
    for (int rt = 0; rt < 2; ++rt)
#pragma unroll
        for (int ct = 0; ct < 8; ++ct) a2[rt][ct] = zero4f();
#pragma unroll
    for (int ks = 0; ks < 4; ++ks) {
        bf16x8 xa[2];
        if (ks < 2) {
#pragma unroll
            for (int rt = 0; rt < 2; ++rt) {
                int rr = rt * 16 + lr;
                int byo = (rr * 128 + (ks * 32 + lg * 8) * 2) ^ ((rr & 7) << 4);
                xa[rt] = *(const bf16x8*)(tlw + byo);
            }
        } else {
#pragma unroll
            for (int rt = 0; rt < 2; ++rt)
                xa[rt] = *(const bf16x8*)(x2 + (size_t)(m0 + rt * 16 + lr) * 64 +
                                          (ks - 2) * 32 + lg * 8);
        }
#pragma unroll
        for (int ct = 0; ct < 8; ++ct) {
            bf16x8 wfr = *(const bf16x8*)(w4l + (size_t)((ks * 8 + ct) * 64 + lane) * 8);
#pragma unroll
            for (int rt = 0; rt < 2; ++rt) a2[rt][ct] = MFMA16(wfr, xa[rt], a2[rt][ct]);
        }
    }
#pragma unroll
    for (int rt = 0; rt < 2; ++rt) {
        size_t r = (size_t)(m0 + rt * 16 + lr);
#pragma unroll
        for (int ct = 0; ct < 8; ++ct) {
            int j0 = ct * 16 + lg * 4;
            f32x4 s4 = *(const f32x4*)(sc4 + j0), h4 = *(const f32x4*)(sh4 + j0);
            f32x4 a = a2[rt][ct];
            f32x4 o;
#pragma unroll
            for (int b = 0; b < 4; ++b) o[b] = hsw(a[b] * s4[b] + h4[b]);
            *(f32x4*)(out + r * 128 + j0) = o;
        }
    }
}

extern "C" void kernel_launch(void* const* d_in, const int* in_sizes, int n_in,
                              void* d_out, int out_size, void* d_ws, size_t ws_size,
                              hipStream_t stream) {
    const float* x      = (const float*)d_in[0];
    const float* cv1_w  = (const float*)d_in[1];
    const float* cv1_bn = (const float*)d_in[2];
    const float* m0c1w  = (const float*)d_in[3];
    const float* m0c1b  = (const float*)d_in[4];
    const float* m0c2w  = (const float*)d_in[5];
    const float* m0c2b  = (const float*)d_in[6];
    const float* m1c1w  = (const float*)d_in[7];
    const float* m1c1b  = (const float*)d_in[8];
    const float* m1c2w  = (const float*)d_in[9];
    const float* m1c2b  = (const float*)d_in[10];
    const float* cv3_w  = (const float*)d_in[11];
    const float* cv2p_w = (const float*)d_in[12];
    const float* bn_cat = (const float*)d_in[13];
    const float* cv4_w  = (const float*)d_in[14];
    const float* cv4_bn = (const float*)d_in[15];
    float* out = (float*)d_out;

    const size_t M = (size_t)16 * 160 * 160;  // 409600
    bf16* y  = (bf16*)d_ws;                   // [M,64]
    bf16* x2 = y + M * 64;                    // [M,64]
    bf16* h  = x2 + M * 64;                   // [M,64]

    dim3 blk(256);
    k_head<<<dim3((int)(M / 128)), blk, 0, stream>>>(x, cv1_w, cv1_bn, cv2p_w, bn_cat, y, x2);
    k_cb64<<<dim3((int)(M / 256)), blk, 0, stream>>>(y, m0c1w, m0c1b, h);
    k_c3 <<<dim3((int)(M / 256)), blk, 0, stream>>>(h, m0c2w, m0c2b, y);
    k_cb64<<<dim3((int)(M / 256)), blk, 0, stream>>>(y, m1c1w, m1c1b, h);
    k_c3 <<<dim3((int)(M / 256)), blk, 0, stream>>>(h, m1c2w, m1c2b, y);
    k_tail<<<dim3((int)(M / 128)), blk, 0, stream>>>(y, x2, cv3_w, cv4_w, bn_cat, cv4_bn, out);
}